// Round 14
// baseline (961.702 us; speedup 1.0000x reference)
//
#include <hip/hip_runtime.h>

// MixerBlock: B=8, T=2048, E=1024, H=16, HD=64, DFF=4096, DC=4
// r14: G3/G4 use gemm_dir — LDS-FREE direct-fragment GEMM:
//   fragment layout == global layout (A row-major, Bt N-major): lane l15 ->
//   row, lk -> 16B k-slot, so global_load_dwordx4 yields MFMA frags directly.
//   No LDS, no staging, no barriers; 2-bank software pipeline (static idx),
//   each of 8 waves is an independent stream; L1/L2 absorb the x4/x2 reuse.
// G1/G2 keep r13's gemm256q (in-run control). Scans vectorized (r13).

#define TT 2048
#define EE 1024
#define HHD 64
#define MROWS 16384
#define SC_L 64

typedef __bf16 bf16x8 __attribute__((ext_vector_type(8)));
typedef float f32x4 __attribute__((ext_vector_type(4)));
typedef unsigned short u16;
typedef unsigned int u32;
typedef u16 u16x8 __attribute__((ext_vector_type(8)));

__device__ __forceinline__ u16 f2bf(float f) {
  u32 u = __builtin_bit_cast(u32, f);
  u += 0x7FFFu + ((u >> 16) & 1u);      // round-to-nearest-even
  return (u16)(u >> 16);
}
__device__ __forceinline__ float bf2f(u16 s) {
  u32 u = ((u32)s) << 16;
  return __builtin_bit_cast(float, u);
}
__device__ __forceinline__ float gelu_f(float x) {
  float x2 = x * x;
  float e = -1.5957691216057308f * x * __builtin_fmaf(0.044715f, x2, 1.0f);
  return x * __builtin_amdgcn_rcpf(1.0f + __expf(e));
}
__device__ __forceinline__ void gload_lds16(const void* g, void* l) {
  __builtin_amdgcn_global_load_lds(
      (const __attribute__((address_space(1))) u32*)g,
      (__attribute__((address_space(3))) u32*)l, 16, 0, 0);
}
__device__ __forceinline__ void wg_barrier() {
  asm volatile("" ::: "memory");
  __builtin_amdgcn_s_barrier();
  asm volatile("" ::: "memory");
}

// ---------------- weight transpose + cast
__global__ __launch_bounds__(256) void transpose_to_bf16(
    const float* __restrict__ src, u16* __restrict__ dst, int R, int C,
    long sbs, long dbs) {
  __shared__ float tile[32][33];
  src += (long)blockIdx.z * sbs;
  dst += (long)blockIdx.z * dbs;
  int c0 = blockIdx.x * 32, r0 = blockIdx.y * 32;
  int tx = threadIdx.x, ty = threadIdx.y;
#pragma unroll
  for (int i = 0; i < 4; i++)
    tile[ty + i * 8][tx] = src[(long)(r0 + ty + i * 8) * C + c0 + tx];
  __syncthreads();
#pragma unroll
  for (int i = 0; i < 4; i++)
    dst[(long)(c0 + ty + i * 8) * R + r0 + tx] = f2bf(tile[tx][ty + i * 8]);
}

// ---------------- LayerNorm over E=1024
__global__ __launch_bounds__(256) void ln_to_bf16(
    const float* __restrict__ x, const float* __restrict__ gam,
    const float* __restrict__ bet, u16* __restrict__ y) {
  int row = blockIdx.x;
  int tid = threadIdx.x;
  float4 v = ((const float4*)x)[row * 256 + tid];
  float s = v.x + v.y + v.z + v.w;
  float s2 = v.x * v.x + v.y * v.y + v.z * v.z + v.w * v.w;
#pragma unroll
  for (int off = 1; off < 64; off <<= 1) {
    s += __shfl_xor(s, off);
    s2 += __shfl_xor(s2, off);
  }
  __shared__ float red[8];
  int w = tid >> 6;
  if ((tid & 63) == 0) { red[w] = s; red[4 + w] = s2; }
  __syncthreads();
  s = red[0] + red[1] + red[2] + red[3];
  s2 = red[4] + red[5] + red[6] + red[7];
  float mu = s * (1.0f / 1024.0f);
  float var = s2 * (1.0f / 1024.0f) - mu * mu;
  float rstd = rsqrtf(var + 1e-5f);
  int e0 = tid * 4;
  ushort4 o;
  o.x = f2bf((v.x - mu) * rstd * gam[e0 + 0] + bet[e0 + 0]);
  o.y = f2bf((v.y - mu) * rstd * gam[e0 + 1] + bet[e0 + 1]);
  o.z = f2bf((v.z - mu) * rstd * gam[e0 + 2] + bet[e0 + 2]);
  o.w = f2bf((v.w - mu) * rstd * gam[e0 + 3] + bet[e0 + 3]);
  ((ushort4*)y)[row * 256 + tid] = o;
}

// ---------------- LDS-free direct-fragment GEMM. 256x256 macro-tile,
// 8 waves (2Mx4N, 128x64/wave), 2-bank pipelined over 32-wide k-steps.
// A: (M x K) bf16 rm. Bt: (N x K) bf16 rm. K % 64 == 0.
// EPI 0: bf16 = acc+bias ; 1: f32 = acc+bias+res ; 2: bf16 = gelu(acc+bias)
template <int EPI>
__global__ __launch_bounds__(512, 1) void gemm_dir(
    const u16* __restrict__ A, const u16* __restrict__ Bt,
    const float* __restrict__ bias, const float* __restrict__ res, void* outp,
    int M, int N, int K, int px, int gxp, int byper) {
  const int tid = threadIdx.x;
  const int w = tid >> 6, lane = tid & 63;
  const int wm = w >> 2, wn = w & 3;
  const int l15 = lane & 15, lk = lane >> 4;

  // T1: L2-locality supertile swizzle (bijective; nwg % 8 == 0 always)
  const int gx = (int)gridDim.x;
  const int bid = (int)blockIdx.y * gx + (int)blockIdx.x;
  const int xcd = bid & 7, i = bid >> 3;
  const int bx = (xcd % gxp) * px + (i % px);
  const int by = (xcd / gxp) * byper + (i / px);
  const int m0 = by * 256, n0 = bx * 256;

  // Fragment base pointers: frag(mi, kt) = 16B at aB + mi*16*K + kt.
  const u16* aB = A + (size_t)(m0 + wm * 128 + l15) * K + lk * 8;
  const u16* bB = Bt + (size_t)(n0 + wn * 64 + l15) * K + lk * 8;
  const size_t rs16 = (size_t)16 * K;

  f32x4 acc[8][4];
  const f32x4 z = {0.f, 0.f, 0.f, 0.f};
#pragma unroll
  for (int mi = 0; mi < 8; mi++)
#pragma unroll
    for (int ni = 0; ni < 4; ni++) acc[mi][ni] = z;

  bf16x8 a0[8], b0v[4], a1[8], b1v[4];

#define LD_A(DST, KO) { \
    _Pragma("unroll") \
    for (int mi = 0; mi < 8; ++mi) \
      DST[mi] = *(const bf16x8*)(aB + mi * rs16 + (KO)); }
#define LD_B(DST, KO) { \
    _Pragma("unroll") \
    for (int ni = 0; ni < 4; ++ni) \
      DST[ni] = *(const bf16x8*)(bB + ni * rs16 + (KO)); }
#define MM(AV, BV) { \
    __builtin_amdgcn_s_setprio(1); \
    _Pragma("unroll") \
    for (int mi = 0; mi < 8; ++mi) \
      _Pragma("unroll") \
      for (int ni = 0; ni < 4; ++ni) \
        acc[mi][ni] = __builtin_amdgcn_mfma_f32_16x16x32_bf16( \
            AV[mi], BV[ni], acc[mi][ni], 0, 0, 0); \
    __builtin_amdgcn_s_setprio(0); }

  LD_A(a0, 0);
  LD_B(b0v, 0);
  const int nk2 = K >> 6;  // pairs of 32-wide k-steps
  for (int kp = 0; kp < nk2; ++kp) {
    const int kb = kp << 6;
    LD_A(a1, kb + 32);      // prefetch odd k-step (lands under MM(a0))
    LD_B(b1v, kb + 32);
    MM(a0, b0v);
    if (kp + 1 < nk2) {     // prefetch next even k-step (lands under MM(a1))
      LD_A(a0, kb + 64);
      LD_B(b0v, kb + 64);
    }
    MM(a1, b1v);
  }
#undef LD_A
#undef LD_B
#undef MM

#pragma unroll
  for (int mi = 0; mi < 8; mi++) {
#pragma unroll
    for (int ni = 0; ni < 4; ni++) {
      int n = n0 + wn * 64 + ni * 16 + l15;       // C/D: col = lane&15
      float bvv = bias[n];
#pragma unroll
      for (int r = 0; r < 4; r++) {
        int m = m0 + wm * 128 + mi * 16 + lk * 4 + r;  // row = (lane>>4)*4 + reg
        size_t idx = (size_t)m * N + n;
        float v = acc[mi][ni][r] + bvv;
        if (EPI == 0) {
          ((u16*)outp)[idx] = f2bf(v);
        } else if (EPI == 1) {
          ((float*)outp)[idx] = v + res[idx];
        } else {
          ((u16*)outp)[idx] = f2bf(gelu_f(v));
        }
      }
    }
  }
}

// ---------------- bf16 GEMM, 256x256, BK=32, quad-buffered, 1 barrier/tile
// (r13, control for G1/G2).
template <int EPI>
__global__ __launch_bounds__(512, 1) void gemm256q(
    const u16* __restrict__ A, const u16* __restrict__ Bt,
    const float* __restrict__ bias, const float* __restrict__ res, void* outp,
    int M, int N, int K, int px, int gxp, int byper) {
  __shared__ u16 lds[65536];
  const int tid = threadIdx.x;
  const int w = tid >> 6, lane = tid & 63;
  const int wm = w >> 2, wn = w & 3;
  const int l15 = lane & 15, lk = lane >> 4;

  const int gx = (int)gridDim.x;
  const int bid = (int)blockIdx.y * gx + (int)blockIdx.x;
  const int xcd = bid & 7, i = bid >> 3;
  const int bx = (xcd % gxp) * px + (i % px);
  const int by = (xcd / gxp) * byper + (i / px);
  const int m0 = by * 256, n0 = bx * 256;

  const int srow = w * 16 + (lane >> 2);
  const int gslot = (lane & 3) ^ ((srow >> 1) & 3);
  const u16* aS = A + (size_t)(m0 + srow) * K + gslot * 8;
  const u16* aS2 = A + (size_t)(m0 + 128 + srow) * K +
                   (((lane & 3) ^ (((128 + srow) >> 1) & 3)) * 8);
  const u16* bS = Bt + (size_t)(n0 + srow) * K + gslot * 8;
  const u16* bS2 = Bt + (size_t)(n0 + 128 + srow) * K +
                   (((lane & 3) ^ (((128 + srow) >> 1) & 3)) * 8);

  f32x4 acc[8][4];
  const f32x4 z = {0.f, 0.f, 0.f, 0.f};
#pragma unroll
  for (int mi = 0; mi < 8; mi++)
#pragma unroll
    for (int ni = 0; ni < 4; ni++) acc[mi][ni] = z;

  const int sl = (lk ^ ((l15 >> 1) & 3)) * 8;

#define STAGE(BUF, T_) { \
    u16* lb = lds + (BUF) * 16384 + w * 512; \
    const int kt = (T_) << 5; \
    gload_lds16(aS + kt, lb); \
    gload_lds16(aS2 + kt, lb + 4096); \
    gload_lds16(bS + kt, lb + 8192); \
    gload_lds16(bS2 + kt, lb + 12288); }

  const int nt = K >> 5;
  STAGE(0, 0);
  STAGE(1, 1);

  for (int t = 0; t < nt; ++t) {
    if (t + 2 < nt) {
      STAGE((t + 2) & 3, t + 2);
      asm volatile("s_waitcnt vmcnt(8)" ::: "memory");
    } else if (t + 1 < nt) {
      asm volatile("s_waitcnt vmcnt(4)" ::: "memory");
    } else {
      asm volatile("s_waitcnt vmcnt(0)" ::: "memory");
    }
    wg_barrier();

    const u16* lA = lds + (t & 3) * 16384;
    const u16* lB = lA + 8192;
    bf16x8 bq[4];
    {
      const u16* bp = lB + (wn * 64 + l15) * 32 + sl;
#pragma unroll
      for (int ni = 0; ni < 4; ni++) bq[ni] = *(const bf16x8*)(bp + ni * 512);
    }
    const u16* ap = lA + (wm * 128 + l15) * 32 + sl;
    __builtin_amdgcn_s_setprio(1);
#pragma unroll
    for (int mi = 0; mi < 8; mi++) {
      bf16x8 af = *(const bf16x8*)(ap + mi * 512);
#pragma unroll
      for (int ni = 0; ni < 4; ni++)
        acc[mi][ni] = __builtin_amdgcn_mfma_f32_16x16x32_bf16(af, bq[ni],
                                                              acc[mi][ni], 0, 0, 0);
    }
    __builtin_amdgcn_s_setprio(0);
  }
#undef STAGE

#pragma unroll
  for (int mi = 0; mi < 8; mi++) {
#pragma unroll
    for (int ni = 0; ni < 4; ni++) {
      int n = n0 + wn * 64 + ni * 16 + l15;
      float bvv = bias[n];
#pragma unroll
      for (int r = 0; r < 4; r++) {
        int m = m0 + wm * 128 + mi * 16 + lk * 4 + r;
        size_t idx = (size_t)m * N + n;
        float v = acc[mi][ni][r] + bvv;
        if (EPI == 0) {
          ((u16*)outp)[idx] = f2bf(v);
        } else if (EPI == 1) {
          ((float*)outp)[idx] = v + res[idx];
        } else {
          ((u16*)outp)[idx] = f2bf(gelu_f(v));
        }
      }
    }
  }
}

// ---------------- causal decay scan, vectorized 8 f/thread.
__global__ __launch_bounds__(64) void scan_carry(
    const u16* __restrict__ p, const float* __restrict__ mix_w,
    const float* __restrict__ decay, float* __restrict__ carry) {
  int chunk = blockIdx.x * 8 + (threadIdx.x >> 3);
  int fg = threadIdx.x & 7;
  int c = chunk & 31, h = (chunk >> 5) & 15, b = chunk >> 9;
  float d = fminf(fmaxf(decay[h], 0.9f), 1.0f);
  float r = powf(d, 0.25f);
  size_t base = (((size_t)b * TT + c * SC_L) * EE + h * HHD + fg * 8) >> 3;
  const u16x8* p8 = (const u16x8*)p;
  const float* mw = mix_w + h * TT + c * SC_L;
  bool isRow = (h >= 8);
  float S[8] = {0.f, 0.f, 0.f, 0.f, 0.f, 0.f, 0.f, 0.f};
  for (int t = 0; t < SC_L; t++) {
    u16x8 v = p8[base + (size_t)t * (EE / 8)];
    float wv = isRow ? mw[t] : 1.0f;
#pragma unroll
    for (int j = 0; j < 8; j++) S[j] = r * S[j] + wv * bf2f(v[j]);
  }
  float* cp = carry + chunk * 64 + fg * 8;
#pragma unroll
  for (int j = 0; j < 8; j++) cp[j] = S[j];
}

__global__ __launch_bounds__(64) void scan_apply(
    const u16* __restrict__ p, const float* __restrict__ mix_w,
    const float* __restrict__ mix_b, const float* __restrict__ decay,
    const float* __restrict__ carry, u16* __restrict__ mixed) {
  int chunk = blockIdx.x * 8 + (threadIdx.x >> 3);
  int fg = threadIdx.x & 7;
  int c = chunk & 31, h = (chunk >> 5) & 15, b = chunk >> 9;
  float d = fminf(fmaxf(decay[h], 0.9f), 1.0f);
  float r = powf(d, 0.25f);
  float rl = powf(r, (float)SC_L);
  int cb = chunk - c;
  float S[8] = {0.f, 0.f, 0.f, 0.f, 0.f, 0.f, 0.f, 0.f};
  for (int cc = 0; cc < c; cc++) {
    const float* cp = carry + (cb + cc) * 64 + fg * 8;
#pragma unroll
    for (int j = 0; j < 8; j++) S[j] = rl * S[j] + cp[j];
  }
  size_t base = (((size_t)b * TT + c * SC_L) * EE + h * HHD + fg * 8) >> 3;
  const u16x8* p8 = (const u16x8*)p;
  u16x8* m8 = (u16x8*)mixed;
  const float* mw = mix_w + h * TT + c * SC_L;
  const float* mb = mix_b + h * TT + c * SC_L;
  bool isRow = (h >= 8);
  for (int t = 0; t < SC_L; t++) {
    u16x8 v = p8[base + (size_t)t * (EE / 8)];
    float wq = isRow ? mw[t] : 1.0f;
    float wo = isRow ? 1.0f : mw[t];
    float bb = mb[t];
    u16x8 o;
#pragma unroll
    for (int j = 0; j < 8; j++) {
      S[j] = r * S[j] + wq * bf2f(v[j]);
      o[j] = f2bf(wo * S[j] + bb);
    }
    m8[base + (size_t)t * (EE / 8)] = o;
  }
}

extern "C" void kernel_launch(void* const* d_in, const int* in_sizes, int n_in,
                              void* d_out, int out_size, void* d_ws, size_t ws_size,
                              hipStream_t stream) {
  const float* x = (const float*)d_in[0];
  const float* w_proj = (const float*)d_in[1];
  const float* b_proj = (const float*)d_in[2];
  const float* mix_w = (const float*)d_in[3];
  const float* mix_b = (const float*)d_in[4];
  const float* decay = (const float*)d_in[5];
  const float* out_w = (const float*)d_in[6];
  const float* out_b = (const float*)d_in[7];
  const float* ln1_g = (const float*)d_in[8];
  const float* ln1_b = (const float*)d_in[9];
  const float* ln2_g = (const float*)d_in[10];
  const float* ln2_b = (const float*)d_in[11];
  const float* ff_w1 = (const float*)d_in[12];
  const float* ff_b1 = (const float*)d_in[13];
  const float* ff_w2 = (const float*)d_in[14];
  const float* ff_b2 = (const float*)d_in[15];
  float* out = (float*)d_out;

  // ws layout (MiB): [0,2)Wp [2,4)Wo [4,12)W1 [12,20)W2 [20,52)mixed/g
  //                  [52,180)u (h at 52, p at 84) [180,181)carry
  char* ws = (char*)d_ws;
  const size_t MiB = 1ull << 20;
  u16* wWp = (u16*)(ws + 0 * MiB);
  u16* wWo = (u16*)(ws + 2 * MiB);
  u16* wW1 = (u16*)(ws + 4 * MiB);
  u16* wW2 = (u16*)(ws + 12 * MiB);
  u16* wMix = (u16*)(ws + 20 * MiB);
  u16* wH = (u16*)(ws + 52 * MiB);
  u16* wP = (u16*)(ws + 84 * MiB);
  u16* wU = (u16*)(ws + 52 * MiB);
  float* wCarry = (float*)(ws + 180 * MiB);

  dim3 tb(32, 8);
  transpose_to_bf16<<<dim3(2, 32, 16), tb, 0, stream>>>(w_proj, wWp, 1024, 64,
                                                        65536L, 65536L);
  transpose_to_bf16<<<dim3(32, 32, 1), tb, 0, stream>>>(out_w, wWo, 1024, 1024, 0L, 0L);
  transpose_to_bf16<<<dim3(128, 32, 1), tb, 0, stream>>>(ff_w1, wW1, 1024, 4096, 0L, 0L);
  transpose_to_bf16<<<dim3(32, 128, 1), tb, 0, stream>>>(ff_w2, wW2, 4096, 1024, 0L, 0L);

  ln_to_bf16<<<dim3(MROWS), dim3(256), 0, stream>>>(x, ln1_g, ln1_b, wH);

  // G1: control (r13 LDS kernel). px=4, gxp=1, byper=8
  gemm256q<0><<<dim3(4, 64), dim3(512), 0, stream>>>(
      wH, wWp, b_proj, (const float*)nullptr, (void*)wP, MROWS, 1024, 1024,
      4, 1, 8);

  scan_carry<<<dim3(512), dim3(64), 0, stream>>>(wP, mix_w, decay, wCarry);
  scan_apply<<<dim3(512), dim3(64), 0, stream>>>(wP, mix_w, mix_b, decay, wCarry, wMix);

  // G2: control
  gemm256q<1><<<dim3(4, 64), dim3(512), 0, stream>>>(
      wMix, wWo, out_b, x, (void*)out, MROWS, 1024, 1024,
      4, 1, 8);

  ln_to_bf16<<<dim3(MROWS), dim3(256), 0, stream>>>(out, ln2_g, ln2_b, wMix);

  // G3: LDS-free direct. px=4, gxp=4, byper=32
  gemm_dir<2><<<dim3(16, 64), dim3(512), 0, stream>>>(
      wMix, wW1, ff_b1, (const float*)nullptr, (void*)wU, MROWS, 4096, 1024,
      4, 4, 32);

  // G4: LDS-free direct. px=2, gxp=2, byper=16
  gemm_dir<1><<<dim3(4, 64), dim3(512), 0, stream>>>(
      wU, wW2, ff_b2, out, (void*)out, MROWS, 1024, 4096,
      2, 2, 16);
}

// Round 15
// 505.053 us; speedup vs baseline: 1.9042x; 1.9042x over previous
//
#include <hip/hip_runtime.h>

// MixerBlock: B=8, T=2048, E=1024, H=16, HD=64, DFF=4096, DC=4
// GEMM r15: r13 quad-buffer base (best, 520us) + EXPLICIT per-fragment
// counted lgkmcnt interleave in the compute body (rule #18):
//   issue 12 ds_read_b128 via inline asm (bq0-3, af0-7), then
//   WAITK(7)->MFMA(af0), WAITK(6)->MFMA(af1), ... WAITK(0)->MFMA(af7)
//   (each WAITK = s_waitcnt lgkmcnt(N) + sched_barrier(0))
// so MFMA batch mi starts when ITS fragment lands instead of after a
// conservative full drain — reads of later frags stream under MFMAs.
// Everything else frozen from r13: 256x256 tile, BK=32, 8 waves (2Mx4N),
// 4x32KiB buffers, 1 barrier/tile, counted vmcnt(8/4/0), XOR swizzle
// (slot ^ (row>>1)&3, pre-swizzled source), supertile XCD swizzle,
// vectorized scans.

#define TT 2048
#define EE 1024
#define HHD 64
#define MROWS 16384
#define SC_L 64

typedef __bf16 bf16x8 __attribute__((ext_vector_type(8)));
typedef float f32x4 __attribute__((ext_vector_type(4)));
typedef unsigned short u16;
typedef unsigned int u32;
typedef u16 u16x8 __attribute__((ext_vector_type(8)));

__device__ __forceinline__ u16 f2bf(float f) {
  u32 u = __builtin_bit_cast(u32, f);
  u += 0x7FFFu + ((u >> 16) & 1u);      // round-to-nearest-even
  return (u16)(u >> 16);
}
__device__ __forceinline__ float bf2f(u16 s) {
  u32 u = ((u32)s) << 16;
  return __builtin_bit_cast(float, u);
}
__device__ __forceinline__ float gelu_f(float x) {
  float x2 = x * x;
  float e = -1.5957691216057308f * x * __builtin_fmaf(0.044715f, x2, 1.0f);
  return x * __builtin_amdgcn_rcpf(1.0f + __expf(e));
}
__device__ __forceinline__ void gload_lds16(const void* g, void* l) {
  __builtin_amdgcn_global_load_lds(
      (const __attribute__((address_space(1))) u32*)g,
      (__attribute__((address_space(3))) u32*)l, 16, 0, 0);
}
__device__ __forceinline__ void wg_barrier() {
  asm volatile("" ::: "memory");
  __builtin_amdgcn_s_barrier();
  asm volatile("" ::: "memory");
}

// ---------------- weight transpose + cast
__global__ __launch_bounds__(256) void transpose_to_bf16(
    const float* __restrict__ src, u16* __restrict__ dst, int R, int C,
    long sbs, long dbs) {
  __shared__ float tile[32][33];
  src += (long)blockIdx.z * sbs;
  dst += (long)blockIdx.z * dbs;
  int c0 = blockIdx.x * 32, r0 = blockIdx.y * 32;
  int tx = threadIdx.x, ty = threadIdx.y;
#pragma unroll
  for (int i = 0; i < 4; i++)
    tile[ty + i * 8][tx] = src[(long)(r0 + ty + i * 8) * C + c0 + tx];
  __syncthreads();
#pragma unroll
  for (int i = 0; i < 4; i++)
    dst[(long)(c0 + ty + i * 8) * R + r0 + tx] = f2bf(tile[tx][ty + i * 8]);
}

// ---------------- LayerNorm over E=1024
__global__ __launch_bounds__(256) void ln_to_bf16(
    const float* __restrict__ x, const float* __restrict__ gam,
    const float* __restrict__ bet, u16* __restrict__ y) {
  int row = blockIdx.x;
  int tid = threadIdx.x;
  float4 v = ((const float4*)x)[row * 256 + tid];
  float s = v.x + v.y + v.z + v.w;
  float s2 = v.x * v.x + v.y * v.y + v.z * v.z + v.w * v.w;
#pragma unroll
  for (int off = 1; off < 64; off <<= 1) {
    s += __shfl_xor(s, off);
    s2 += __shfl_xor(s2, off);
  }
  __shared__ float red[8];
  int w = tid >> 6;
  if ((tid & 63) == 0) { red[w] = s; red[4 + w] = s2; }
  __syncthreads();
  s = red[0] + red[1] + red[2] + red[3];
  s2 = red[4] + red[5] + red[6] + red[7];
  float mu = s * (1.0f / 1024.0f);
  float var = s2 * (1.0f / 1024.0f) - mu * mu;
  float rstd = rsqrtf(var + 1e-5f);
  int e0 = tid * 4;
  ushort4 o;
  o.x = f2bf((v.x - mu) * rstd * gam[e0 + 0] + bet[e0 + 0]);
  o.y = f2bf((v.y - mu) * rstd * gam[e0 + 1] + bet[e0 + 1]);
  o.z = f2bf((v.z - mu) * rstd * gam[e0 + 2] + bet[e0 + 2]);
  o.w = f2bf((v.w - mu) * rstd * gam[e0 + 3] + bet[e0 + 3]);
  ((ushort4*)y)[row * 256 + tid] = o;
}

// ---------------- bf16 GEMM, 256x256, BK=32, quad-buffer, 1 barrier/tile,
// asm ds_read + counted lgkmcnt interleave.
// A: (M x K) bf16 rm. Bt: (N x K) bf16 rm.
// LDS buf q at byte q*32768: A bytes [0,16384), B [16384,32768).
// EPI 0: bf16 = acc+bias ; 1: f32 = acc+bias+res ; 2: bf16 = gelu(acc+bias)
template <int EPI>
__global__ __launch_bounds__(512, 1) void gemm256q(
    const u16* __restrict__ A, const u16* __restrict__ Bt,
    const float* __restrict__ bias, const float* __restrict__ res, void* outp,
    int M, int N, int K, int px, int gxp, int byper) {
  __shared__ u16 lds[65536];  // 128 KiB = 4 x 32 KiB buffers
  const int tid = threadIdx.x;
  const int w = tid >> 6, lane = tid & 63;
  const int wm = w >> 2, wn = w & 3;
  const int l15 = lane & 15, lk = lane >> 4;

  // T1: L2-locality supertile swizzle (bijective; nwg % 8 == 0 always)
  const int gx = (int)gridDim.x;
  const int bid = (int)blockIdx.y * gx + (int)blockIdx.x;
  const int xcd = bid & 7, i = bid >> 3;
  const int bx = (xcd % gxp) * px + (i % px);
  const int by = (xcd / gxp) * byper + (i / px);
  const int m0 = by * 256, n0 = bx * 256;

  // Staging (r13): thread -> row srow (0..127, +128 via 2nd load), LDS slot
  // lane&3; global slot pre-swizzled by (row>>1)&3.
  const int srow = w * 16 + (lane >> 2);
  const int gslot = (lane & 3) ^ ((srow >> 1) & 3);
  const u16* aS = A + (size_t)(m0 + srow) * K + gslot * 8;
  const u16* aS2 = A + (size_t)(m0 + 128 + srow) * K +
                   (((lane & 3) ^ (((128 + srow) >> 1) & 3)) * 8);
  const u16* bS = Bt + (size_t)(n0 + srow) * K + gslot * 8;
  const u16* bS2 = Bt + (size_t)(n0 + 128 + srow) * K +
                   (((lane & 3) ^ (((128 + srow) >> 1) & 3)) * 8);

  f32x4 acc[8][4];
  const f32x4 z = {0.f, 0.f, 0.f, 0.f};
#pragma unroll
  for (int mi = 0; mi < 8; mi++)
#pragma unroll
    for (int ni = 0; ni < 4; ni++) acc[mi][ni] = z;

  // Read-side swizzle (r13): sl = (lk ^ ((l15>>1)&3)) * 8 u16.
  const int sl = (lk ^ ((l15 >> 1) & 3)) * 8;
  const u32 ldsB = (u32)(uintptr_t)(void*)lds;
  const u32 aOffB = ldsB + (u32)(((wm * 128 + l15) * 32 + sl) * 2);
  const u32 bOffB = ldsB + 16384u + (u32)(((wn * 64 + l15) * 32 + sl) * 2);

#define STAGE(BUF, T_) { \
    u16* lb = lds + (BUF) * 16384 + w * 512; \
    const int kt = (T_) << 5; \
    gload_lds16(aS + kt, lb); \
    gload_lds16(aS2 + kt, lb + 4096); \
    gload_lds16(bS + kt, lb + 8192); \
    gload_lds16(bS2 + kt, lb + 12288); }

#define DS_RD(D, ADDR, OFF) \
    asm volatile("ds_read_b128 %0, %1 offset:" #OFF : "=v"(D) : "v"(ADDR))
#define WAITK(N_) { \
    asm volatile("s_waitcnt lgkmcnt(" #N_ ")" ::: "memory"); \
    __builtin_amdgcn_sched_barrier(0); }
#define MFMA4(MI, AF) { \
    acc[MI][0] = __builtin_amdgcn_mfma_f32_16x16x32_bf16(AF, bq0, acc[MI][0], 0, 0, 0); \
    acc[MI][1] = __builtin_amdgcn_mfma_f32_16x16x32_bf16(AF, bq1, acc[MI][1], 0, 0, 0); \
    acc[MI][2] = __builtin_amdgcn_mfma_f32_16x16x32_bf16(AF, bq2, acc[MI][2], 0, 0, 0); \
    acc[MI][3] = __builtin_amdgcn_mfma_f32_16x16x32_bf16(AF, bq3, acc[MI][3], 0, 0, 0); }

  const int nt = K >> 5;
  STAGE(0, 0);
  STAGE(1, 1);

  for (int t = 0; t < nt; ++t) {
    if (t + 2 < nt) {
      STAGE((t + 2) & 3, t + 2);
      asm volatile("s_waitcnt vmcnt(8)" ::: "memory");   // forces tile t's own
    } else if (t + 1 < nt) {
      asm volatile("s_waitcnt vmcnt(4)" ::: "memory");
    } else {
      asm volatile("s_waitcnt vmcnt(0)" ::: "memory");
    }
    wg_barrier();  // only barrier: everyone's t-data resident; fences stage
                   // into buf[(t+2)&3] vs its old readers (>=2 barriers back).

    const u32 bufO = (u32)(t & 3) * 32768u;
    const u32 aA = aOffB + bufO;
    const u32 bA = bOffB + bufO;
    bf16x8 bq0, bq1, bq2, bq3, af0, af1, af2, af3, af4, af5, af6, af7;
    DS_RD(bq0, bA, 0);
    DS_RD(bq1, bA, 1024);
    DS_RD(bq2, bA, 2048);
    DS_RD(bq3, bA, 3072);
    DS_RD(af0, aA, 0);
    DS_RD(af1, aA, 1024);
    DS_RD(af2, aA, 2048);
    DS_RD(af3, aA, 3072);
    DS_RD(af4, aA, 4096);
    DS_RD(af5, aA, 5120);
    DS_RD(af6, aA, 6144);
    DS_RD(af7, aA, 7168);
    // Per-fragment counted waits: MFMA batch mi starts when af[mi] lands
    // (12 reads issued; after read 5+mi lands, outstanding = 7-mi).
    WAITK(7);
    __builtin_amdgcn_s_setprio(1);
    MFMA4(0, af0);
    WAITK(6);
    MFMA4(1, af1);
    WAITK(5);
    MFMA4(2, af2);
    WAITK(4);
    MFMA4(3, af3);
    WAITK(3);
    MFMA4(4, af4);
    WAITK(2);
    MFMA4(5, af5);
    WAITK(1);
    MFMA4(6, af6);
    WAITK(0);
    MFMA4(7, af7);
    __builtin_amdgcn_s_setprio(0);
    // no trailing barrier (quad-buffer ledger, r13)
  }
#undef STAGE
#undef DS_RD
#undef WAITK
#undef MFMA4

#pragma unroll
  for (int mi = 0; mi < 8; mi++) {
#pragma unroll
    for (int ni = 0; ni < 4; ni++) {
      int n = n0 + wn * 64 + ni * 16 + l15;       // C/D: col = lane&15
      float bvv = bias[n];
#pragma unroll
      for (int r = 0; r < 4; r++) {
        int m = m0 + wm * 128 + mi * 16 + lk * 4 + r;  // row = (lane>>4)*4 + reg
        size_t idx = (size_t)m * N + n;
        float v = acc[mi][ni][r] + bvv;
        if (EPI == 0) {
          ((u16*)outp)[idx] = f2bf(v);
        } else if (EPI == 1) {
          ((float*)outp)[idx] = v + res[idx];
        } else {
          ((u16*)outp)[idx] = f2bf(gelu_f(v));
        }
      }
    }
  }
}

// ---------------- causal decay scan, vectorized 8 f/thread.
__global__ __launch_bounds__(64) void scan_carry(
    const u16* __restrict__ p, const float* __restrict__ mix_w,
    const float* __restrict__ decay, float* __restrict__ carry) {
  int chunk = blockIdx.x * 8 + (threadIdx.x >> 3);
  int fg = threadIdx.x & 7;
  int c = chunk & 31, h = (chunk >> 5) & 15, b = chunk >> 9;
  float d = fminf(fmaxf(decay[h], 0.9f), 1.0f);
  float r = powf(d, 0.25f);
  size_t base = (((size_t)b * TT + c * SC_L) * EE + h * HHD + fg * 8) >> 3;
  const u16x8* p8 = (const u16x8*)p;
  const float* mw = mix_w + h * TT + c * SC_L;
  bool isRow = (h >= 8);
  float S[8] = {0.f, 0.f, 0.f, 0.f, 0.f, 0.f, 0.f, 0.f};
  for (int t = 0; t < SC_L; t++) {
    u16x8 v = p8[base + (size_t)t * (EE / 8)];
    float wv = isRow ? mw[t] : 1.0f;
#pragma unroll
    for (int j = 0; j < 8; j++) S[j] = r * S[j] + wv * bf2f(v[j]);
  }
  float* cp = carry + chunk * 64 + fg * 8;
#pragma unroll
  for (int j = 0; j < 8; j++) cp[j] = S[j];
}

__global__ __launch_bounds__(64) void scan_apply(
    const u16* __restrict__ p, const float* __restrict__ mix_w,
    const float* __restrict__ mix_b, const float* __restrict__ decay,
    const float* __restrict__ carry, u16* __restrict__ mixed) {
  int chunk = blockIdx.x * 8 + (threadIdx.x >> 3);
  int fg = threadIdx.x & 7;
  int c = chunk & 31, h = (chunk >> 5) & 15, b = chunk >> 9;
  float d = fminf(fmaxf(decay[h], 0.9f), 1.0f);
  float r = powf(d, 0.25f);
  float rl = powf(r, (float)SC_L);
  int cb = chunk - c;
  float S[8] = {0.f, 0.f, 0.f, 0.f, 0.f, 0.f, 0.f, 0.f};
  for (int cc = 0; cc < c; cc++) {
    const float* cp = carry + (cb + cc) * 64 + fg * 8;
#pragma unroll
    for (int j = 0; j < 8; j++) S[j] = rl * S[j] + cp[j];
  }
  size_t base = (((size_t)b * TT + c * SC_L) * EE + h * HHD + fg * 8) >> 3;
  const u16x8* p8 = (const u16x8*)p;
  u16x8* m8 = (u16x8*)mixed;
  const float* mw = mix_w + h * TT + c * SC_L;
  const float* mb = mix_b + h * TT + c * SC_L;
  bool isRow = (h >= 8);
  for (int t = 0; t < SC_L; t++) {
    u16x8 v = p8[base + (size_t)t * (EE / 8)];
    float wq = isRow ? mw[t] : 1.0f;
    float wo = isRow ? 1.0f : mw[t];
    float bb = mb[t];
    u16x8 o;
#pragma unroll
    for (int j = 0; j < 8; j++) {
      S[j] = r * S[j] + wq * bf2f(v[j]);
      o[j] = f2bf(wo * S[j] + bb);
    }
    m8[base + (size_t)t * (EE / 8)] = o;
  }
}

extern "C" void kernel_launch(void* const* d_in, const int* in_sizes, int n_in,
                              void* d_out, int out_size, void* d_ws, size_t ws_size,
                              hipStream_t stream) {
  const float* x = (const float*)d_in[0];
  const float* w_proj = (const float*)d_in[1];
  const float* b_proj = (const float*)d_in[2];
  const float* mix_w = (const float*)d_in[3];
  const float* mix_b = (const float*)d_in[4];
  const float* decay = (const float*)d_in[5];
  const float* out_w = (const float*)d_in[6];
  const float* out_b = (const float*)d_in[7];
  const float* ln1_g = (const float*)d_in[8];
  const float* ln1_b = (const float*)d_in[9];
  const float* ln2_g = (const float*)d_in[10];
  const float* ln2_b = (const float*)d_in[11];
  const float* ff_w1 = (const float*)d_in[12];
  const float* ff_b1 = (const float*)d_in[13];
  const float* ff_w2 = (const float*)d_in[14];
  const float* ff_b2 = (const float*)d_in[15];
  float* out = (float*)d_out;

  // ws layout (MiB): [0,2)Wp [2,4)Wo [4,12)W1 [12,20)W2 [20,52)mixed/g
  //                  [52,180)u (h at 52, p at 84) [180,181)carry
  char* ws = (char*)d_ws;
  const size_t MiB = 1ull << 20;
  u16* wWp = (u16*)(ws + 0 * MiB);
  u16* wWo = (u16*)(ws + 2 * MiB);
  u16* wW1 = (u16*)(ws + 4 * MiB);
  u16* wW2 = (u16*)(ws + 12 * MiB);
  u16* wMix = (u16*)(ws + 20 * MiB);
  u16* wH = (u16*)(ws + 52 * MiB);
  u16* wP = (u16*)(ws + 84 * MiB);
  u16* wU = (u16*)(ws + 52 * MiB);
  float* wCarry = (float*)(ws + 180 * MiB);

  dim3 tb(32, 8);
  transpose_to_bf16<<<dim3(2, 32, 16), tb, 0, stream>>>(w_proj, wWp, 1024, 64,
                                                        65536L, 65536L);
  transpose_to_bf16<<<dim3(32, 32, 1), tb, 0, stream>>>(out_w, wWo, 1024, 1024, 0L, 0L);
  transpose_to_bf16<<<dim3(128, 32, 1), tb, 0, stream>>>(ff_w1, wW1, 1024, 4096, 0L, 0L);
  transpose_to_bf16<<<dim3(32, 128, 1), tb, 0, stream>>>(ff_w2, wW2, 4096, 1024, 0L, 0L);

  ln_to_bf16<<<dim3(MROWS), dim3(256), 0, stream>>>(x, ln1_g, ln1_b, wH);

  // G1: px=4 (B 2MB fully L2/XCD), gxp=1, byper=8
  gemm256q<0><<<dim3(4, 64), dim3(512), 0, stream>>>(
      wH, wWp, b_proj, (const float*)nullptr, (void*)wP, MROWS, 1024, 1024,
      4, 1, 8);

  scan_carry<<<dim3(512), dim3(64), 0, stream>>>(wP, mix_w, decay, wCarry);
  scan_apply<<<dim3(512), dim3(64), 0, stream>>>(wP, mix_w, mix_b, decay, wCarry, wMix);

  // G2: same shape as G1
  gemm256q<1><<<dim3(4, 64), dim3(512), 0, stream>>>(
      wMix, wWo, out_b, x, (void*)out, MROWS, 1024, 1024,
      4, 1, 8);

  ln_to_bf16<<<dim3(MROWS), dim3(256), 0, stream>>>(out, ln2_g, ln2_b, wMix);

  // G3: px=4, gxp=4, byper=32
  gemm256q<2><<<dim3(16, 64), dim3(512), 0, stream>>>(
      wMix, wW1, ff_b1, (const float*)nullptr, (void*)wU, MROWS, 4096, 1024,
      4, 4, 32);

  // G4: px=2, gxp=2, byper=16
  gemm256q<1><<<dim3(4, 64), dim3(512), 0, stream>>>(
      wU, wW2, ff_b2, out, (void*)out, MROWS, 1024, 4096,
      2, 2, 16);
}